// Round 10
// baseline (221.364 us; speedup 1.0000x reference)
//
#include <hip/hip_runtime.h>
#include <hip/hip_bf16.h>
#include <math.h>

#define BB 2
#define SS 2048
#define DD 2048
#define NR (BB*(SS-1))      // 4094 valid rows
#define NRP 4096            // padded rows
#define MC_LD 1792          // mega C cols: [head 1024 | p1 512 | p2 128 | p3 32 + pad 96]
#define MT_LD 768           // compact proj layout: [p1 512 | p2 128 | p3 32 | pad]
#define MT_P2 512
#define MT_P3 640

#define L2E 1.4426950408889634f
#define LSE_SHIFT 4.0f
#define LSE_NC (-LSE_SHIFT * L2E)
#define WSCALE 16.0f        // fp8 weight pre-scale (avoids e4m3 subnormals at |w|~0.02)
#define WINV   0.0625f

typedef short  bh8   __attribute__((ext_vector_type(8)));
typedef float  f32x4 __attribute__((ext_vector_type(4)));
typedef long   l64x2 __attribute__((ext_vector_type(2)));   // 16 B = two fp8 MFMA operands

__device__ inline float bfl(unsigned short b) { return __uint_as_float(((unsigned)b) << 16); }
__device__ inline float expsh(float v) { return __builtin_amdgcn_exp2f(fmaf(v, L2E, LSE_NC)); }

__device__ inline float block_sum256(float v) {
    __shared__ float tmp[4];
    #pragma unroll
    for (int o = 32; o > 0; o >>= 1) v += __shfl_down(v, o, 64);
    int lane = threadIdx.x & 63, w = threadIdx.x >> 6;
    if (lane == 0) tmp[w] = v;
    __syncthreads();
    float r = tmp[0] + tmp[1] + tmp[2] + tmp[3];
    __syncthreads();
    return r;
}

// pack 4 floats -> 4 e4m3 bytes (HW cvt, saturating)
__device__ inline unsigned pack_fp8x4(float a, float b, float c, float d) {
    unsigned r = 0;
    r = __builtin_amdgcn_cvt_pk_fp8_f32(a, b, r, false);   // bytes 0-1
    r = __builtin_amdgcn_cvt_pk_fp8_f32(c, d, r, true);    // bytes 2-3
    return r;
}

// ================= stage A: LN + weight casts + index/zero init, ONE launch =================
struct CastSegs {
    const float* src[7];
    void* dst[7];
    int n_src[7];
    int n_tot[7];
    int b0[7];
    int isfp8[7];       // 1: fp8 e4m3 scaled by WSCALE; 0: bf16
};
struct AParams {
    const float* x; const float* gamma; const float* beta;
    unsigned char* h8;                                 // fp8 h [4096][2048]
    CastSegs sg; int castBlocks;
    const int* targets;
    int *relH, *rel1, *rel2, *rel3;
    float *S1, *S2, *out;
};

__global__ __launch_bounds__(256) void stageA(AParams p) {
    int blk = blockIdx.x, tid = threadIdx.x;
    if (blk < NRP) {                                   // ---- LayerNorm role -> fp8 h ----
        int n = blk;
        unsigned char* hr = p.h8 + (size_t)n * DD;
        if (n >= NR) { *(uint2*)(hr + tid * 8) = make_uint2(0,0); return; }
        int b = n / (SS - 1), t = n % (SS - 1);
        const float4* xr = (const float4*)(p.x + (size_t)(b * SS + t) * DD);
        float4 a = xr[tid * 2];
        float4 c = xr[tid * 2 + 1];
        float sum = a.x + a.y + a.z + a.w + c.x + c.y + c.z + c.w;
        sum = block_sum256(sum);
        float mu = sum * (1.0f / DD);
        float d[8] = {a.x-mu, a.y-mu, a.z-mu, a.w-mu, c.x-mu, c.y-mu, c.z-mu, c.w-mu};
        float sq = 0.f;
        #pragma unroll
        for (int i = 0; i < 8; ++i) sq += d[i] * d[i];
        sq = block_sum256(sq);
        float rstd = rsqrtf(sq * (1.0f / DD) + 1e-5f);
        const float4* g4 = (const float4*)p.gamma;
        const float4* be4 = (const float4*)p.beta;
        float4 g1 = g4[tid*2], g2 = g4[tid*2+1];
        float4 b1 = be4[tid*2], b2 = be4[tid*2+1];
        float gg[8] = {g1.x,g1.y,g1.z,g1.w,g2.x,g2.y,g2.z,g2.w};
        float bb[8] = {b1.x,b1.y,b1.z,b1.w,b2.x,b2.y,b2.z,b2.w};
        float o[8];
        #pragma unroll
        for (int i = 0; i < 8; ++i) o[i] = d[i] * rstd * gg[i] + bb[i];
        uint2 pk;
        pk.x = pack_fp8x4(o[0], o[1], o[2], o[3]);
        pk.y = pack_fp8x4(o[4], o[5], o[6], o[7]);
        *(uint2*)(hr + tid * 8) = pk;
        return;
    }
    blk -= NRP;
    if (blk < p.castBlocks) {                          // ---- weight cast role ----
        int k = 0;
        #pragma unroll
        for (int i = 1; i < 7; ++i) if (blk >= p.sg.b0[i]) k = i;
        int i4 = (blk - p.sg.b0[k]) * 1024 + tid * 4;
        if (i4 >= p.sg.n_tot[k]) return;
        float4 v = make_float4(0.f,0.f,0.f,0.f);
        if (i4 < p.sg.n_src[k]) v = *(const float4*)(p.sg.src[k] + i4);
        if (p.sg.isfp8[k]) {
            unsigned pk = pack_fp8x4(v.x * WSCALE, v.y * WSCALE, v.z * WSCALE, v.w * WSCALE);
            *(unsigned*)((unsigned char*)p.sg.dst[k] + i4) = pk;
        } else {
            __align__(8) __hip_bfloat16 o[4] = {
                __float2bfloat16(v.x), __float2bfloat16(v.y),
                __float2bfloat16(v.z), __float2bfloat16(v.w)};
            *(uint2*)((__hip_bfloat16*)p.sg.dst[k] + i4) = *(uint2*)o;
        }
        return;
    }
    blk -= p.castBlocks;                               // ---- init role (16 blocks) ----
    int n = blk * 256 + tid;
    if (n >= NRP) return;
    int lbl = -1;
    if (n < NR) {
        int b = n / (SS - 1), t = n % (SS - 1);
        lbl = p.targets[b * SS + t + 1];
    }
    bool v = n < NR;
    p.relH[n] = v ? (lbl < 1000 ? lbl : 999) : -1;
    int r1 = lbl - 1000;  p.rel1[n] = v ? (r1 < 0 ? 0 : (r1 > 999   ? 999   : r1)) : -1;
    int r2 = lbl - 2000;  p.rel2[n] = v ? (r2 < 0 ? 0 : (r2 > 2999  ? 2999  : r2)) : -1;
    int r3 = lbl - 5000;  p.rel3[n] = v ? (r3 < 0 ? 0 : (r3 > 26999 ? 26999 : r3)) : -1;
    p.S1[n] = 0.f; p.S2[n] = 0.f;
    if (n == 0) p.out[0] = 0.f;
}

// ================= stage B: mega GEMM fp8, 128x128 tile, BK=64, split-K=2 =================
// ds_read_b128 frags at row*64+q*16 (bank-proven); k-permutation trick: identical
// permutation on A and B leaves the k-sum unchanged. [R9-verified]
__global__ __launch_bounds__(256) void mega_sk(
        const unsigned char* __restrict__ A,           // h8 [4096][2048] fp8
        const unsigned char* __restrict__ W,           // w1cat8 [1792][2048] fp8 (x16)
        __hip_bfloat16* __restrict__ P) {              // [2][4096][1792]
    __shared__ __align__(16) unsigned char As[128 * 64];   // 8 KB
    __shared__ __align__(16) unsigned char Ws[128 * 64];   // 8 KB
    int tid = threadIdx.x, wv = tid >> 6, lane = tid & 63;
    int row0 = blockIdx.y * 128, col0 = blockIdx.x * 128;
    int kb = blockIdx.z * 1024, ke = kb + 1024;
    int wrow = (wv >> 1) * 64, wcol = (wv & 1) * 64;
    f32x4 acc[4][4];
    #pragma unroll
    for (int i = 0; i < 4; ++i)
        #pragma unroll
        for (int j = 0; j < 4; ++j) acc[i][j] = (f32x4){0.f,0.f,0.f,0.f};
    int sr = lane >> 2;           // row within 16-row chunk
    int kp = (lane & 3) * 16;     // byte offset within 64B row (staging)
    int mrow = lane & 15;
    int q16 = (lane >> 4) * 16;   // frag b128 byte offset

    for (int k0 = kb; k0 < ke; k0 += 64) {
        __syncthreads();
        #pragma unroll
        for (int i = 0; i < 2; ++i) {
            int chunk = wv * 2 + i;                    // 8 chunks of 16 rows
            int r = chunk * 16 + sr;
            const void* ga = A + (size_t)(row0 + r) * DD + k0 + kp;
            const void* gw = W + (size_t)(col0 + r) * DD + k0 + kp;
            void* la = (char*)As + chunk * 1024 + lane * 16;
            void* lw = (char*)Ws + chunk * 1024 + lane * 16;
            __builtin_amdgcn_global_load_lds(
                (const __attribute__((address_space(1))) void*)ga,
                (__attribute__((address_space(3))) void*)la, 16, 0, 0);
            __builtin_amdgcn_global_load_lds(
                (const __attribute__((address_space(1))) void*)gw,
                (__attribute__((address_space(3))) void*)lw, 16, 0, 0);
        }
        __syncthreads();
        l64x2 af[4], bfr[4];
        #pragma unroll
        for (int t = 0; t < 4; ++t) {
            af[t]  = *(const l64x2*)(As + (wrow + t*16 + mrow) * 64 + q16);
            bfr[t] = *(const l64x2*)(Ws + (wcol + t*16 + mrow) * 64 + q16);
        }
        #pragma unroll
        for (int s = 0; s < 2; ++s)
            #pragma unroll
            for (int i = 0; i < 4; ++i)
                #pragma unroll
                for (int j = 0; j < 4; ++j)
                    acc[i][j] = __builtin_amdgcn_mfma_f32_16x16x32_fp8_fp8(
                        af[i][s], bfr[j][s], acc[i][j], 0, 0, 0);
    }
    __hip_bfloat16* Cz = P + (size_t)blockIdx.z * NRP * MC_LD;
    int ccol = lane & 15, crow = (lane >> 4) * 4;
    #pragma unroll
    for (int i = 0; i < 4; ++i) {
        size_t gr0 = row0 + wrow + i*16 + crow;
        #pragma unroll
        for (int j = 0; j < 4; ++j) {
            size_t gc = col0 + wcol + j*16 + ccol;
            #pragma unroll
            for (int r = 0; r < 4; ++r)
                Cz[(gr0 + r) * MC_LD + gc] = __float2bfloat16(acc[i][j][r] * WINV);
        }
    }
}

// ================= combine: sum partials; head-LSE + gathers; write compact megaT =================
__global__ __launch_bounds__(256) void combine_head(
        const __hip_bfloat16* __restrict__ P,          // [2][4096][1792]
        __hip_bfloat16* __restrict__ megaT,            // [4096][768]
        const int* __restrict__ relH,
        float* __restrict__ S0, float* __restrict__ aux) {
    int n = blockIdx.x, t = threadIdx.x;
    float s = 0.f;
    if (t < 224) {
        int c0 = t * 8;
        bh8 v0 = *(const bh8*)(P + (size_t)n * MC_LD + c0);
        bh8 v1 = *(const bh8*)(P + (size_t)NRP * MC_LD + (size_t)n * MC_LD + c0);
        float v[8];
        #pragma unroll
        for (int e = 0; e < 8; ++e)
            v[e] = bfl(((unsigned short*)&v0)[e]) + bfl(((unsigned short*)&v1)[e]);
        if (c0 < 1024) {                               // head region (t<128)
            int rh = relH[n];
            #pragma unroll
            for (int e = 0; e < 8; ++e) {
                int c = c0 + e;
                if (c < 1003) s += expsh(v[e]);
                if (c == rh) aux[n*8 + 0] = v[e];
                if (c >= 1000 && c < 1003) aux[n*8 + 2 + (c - 1000)] = v[e];
            }
        } else {                                       // proj region -> compact megaT
            __align__(16) __hip_bfloat16 o[8];
            #pragma unroll
            for (int e = 0; e < 8; ++e) o[e] = __float2bfloat16(v[e]);
            *(uint4*)(megaT + (size_t)n * MT_LD + (c0 - 1024)) = *(uint4*)o;
        }
    }
    s = block_sum256(s);
    if (t == 0) S0[n] = s;
}

// ================= streaming tail: A-frags in regs, B from L2, no LDS/barriers =================
// KCH = K/32 chunks, ROWS = rows per block. Pad cols included (logit==0 exactly,
// corrected analytically in final_kernel).
template<int KCH, int ROWS>
__device__ void stream_lse(const __hip_bfloat16* __restrict__ A, int lda,
        const __hip_bfloat16* __restrict__ W, int ldw,
        int rg, int tile0, int ntiles,
        const int* __restrict__ rel, float* __restrict__ S, float* __restrict__ tgt,
        float* red) {
    constexpr int RH = ROWS / 16;
    int tid = threadIdx.x, wv = tid >> 6, lane = tid & 63;
    int q = lane >> 4, cm = lane & 15;
    int row0 = rg * ROWS;
    bh8 af[RH][KCH];
    #pragma unroll
    for (int h = 0; h < RH; ++h)
        #pragma unroll
        for (int c = 0; c < KCH; ++c)
            af[h][c] = *(const bh8*)(A + (size_t)(row0 + h*16 + cm) * lda + c*32 + q*8);
    int rc[RH][4];
    #pragma unroll
    for (int h = 0; h < RH; ++h)
        #pragma unroll
        for (int r = 0; r < 4; ++r)
            rc[h][r] = rel[row0 + h*16 + q*4 + r];
    float s[RH][4];
    #pragma unroll
    for (int h = 0; h < RH; ++h)
        #pragma unroll
        for (int r = 0; r < 4; ++r) s[h][r] = 0.f;

    for (int ot = tile0 + wv; ot < tile0 + ntiles; ot += 4) {
        const __hip_bfloat16* wr = W + (size_t)(ot*16 + cm) * ldw + q*8;
        f32x4 acc[RH][2];
        #pragma unroll
        for (int h = 0; h < RH; ++h) {
            acc[h][0] = (f32x4){0.f,0.f,0.f,0.f};
            acc[h][1] = (f32x4){0.f,0.f,0.f,0.f};
        }
        #pragma unroll
        for (int c = 0; c < KCH; ++c) {
            bh8 bf = *(const bh8*)(wr + c*32);
            #pragma unroll
            for (int h = 0; h < RH; ++h)
                acc[h][c & 1] = __builtin_amdgcn_mfma_f32_16x16x32_bf16(
                    af[h][c], bf, acc[h][c & 1], 0, 0, 0);
        }
        int gc = ot * 16 + cm;
        #pragma unroll
        for (int h = 0; h < RH; ++h)
            #pragma unroll
            for (int r = 0; r < 4; ++r) {
                float v = acc[h][0][r] + acc[h][1][r];
                if (gc == rc[h][r]) tgt[row0 + h*16 + q*4 + r] = v;
                s[h][r] += expsh(v);
            }
    }
    #pragma unroll
    for (int off = 1; off < 16; off <<= 1)
        #pragma unroll
        for (int h = 0; h < RH; ++h)
            #pragma unroll
            for (int r = 0; r < 4; ++r)
                s[h][r] += __shfl_xor(s[h][r], off, 64);
    if (cm == 0)
        #pragma unroll
        for (int h = 0; h < RH; ++h)
            #pragma unroll
            for (int r = 0; r < 4; ++r)
                red[wv * ROWS + h*16 + q*4 + r] = s[h][r];
    __syncthreads();
    if (tid < ROWS)
        atomicAdd(&S[row0 + tid],
                  red[tid] + red[ROWS + tid] + red[2*ROWS + tid] + red[3*ROWS + tid]);
}

__device__ void t3_partial_body(const __hip_bfloat16* megaT,
        const __hip_bfloat16* w2b, float* pS, int idx, int tid, float* red /*[4][32]*/) {
    int rg = idx >> 3, cs = idx & 7;
    int wv = tid >> 6, lane = tid & 63;
    int q = lane >> 4, cm = lane & 15;
    int row0 = rg * 32;
    bh8 af0 = *(const bh8*)(megaT + (size_t)(row0 + cm) * MT_LD + MT_P3 + q * 8);
    bh8 af1 = *(const bh8*)(megaT + (size_t)(row0 + 16 + cm) * MT_LD + MT_P3 + q * 8);
    int tile0 = cs * 211, tile1 = tile0 + 211;
    float s0[4] = {0,0,0,0}, s1[4] = {0,0,0,0};
    bh8 bf = *(const bh8*)(w2b + (size_t)((tile0 + wv) * 16 + cm) * 32 + q * 8);
    for (int ot = tile0 + wv; ot < tile1; ot += 4) {
        int otn = ot + 4;
        bh8 bfn = bf;
        if (otn < tile1)
            bfn = *(const bh8*)(w2b + (size_t)(otn * 16 + cm) * 32 + q * 8);
        f32x4 c0 = __builtin_amdgcn_mfma_f32_16x16x32_bf16(af0, bf, (f32x4){0,0,0,0}, 0, 0, 0);
        f32x4 c1 = __builtin_amdgcn_mfma_f32_16x16x32_bf16(af1, bf, (f32x4){0,0,0,0}, 0, 0, 0);
        #pragma unroll
        for (int r = 0; r < 4; ++r) { s0[r] += expsh(c0[r]); s1[r] += expsh(c1[r]); }
        bf = bfn;
    }
    #pragma unroll
    for (int off = 1; off < 16; off <<= 1)
        #pragma unroll
        for (int r = 0; r < 4; ++r) {
            s0[r] += __shfl_xor(s0[r], off, 64);
            s1[r] += __shfl_xor(s1[r], off, 64);
        }
    if (cm == 0)
        #pragma unroll
        for (int r = 0; r < 4; ++r) {
            red[wv * 32 + q * 4 + r]      = s0[r];
            red[wv * 32 + 16 + q * 4 + r] = s1[r];
        }
    __syncthreads();
    if (tid < 32)
        pS[(size_t)(row0 + tid) * 8 + cs] = red[tid] + red[32 + tid] + red[64 + tid] + red[96 + tid];
}

__device__ void t3_gather_body(const __hip_bfloat16* megaT, const __hip_bfloat16* w2b,
        const int* rel3, float* tt2, int idx, int tid) {
    int n = idx * 256 + tid;
    if (n >= NR) return;
    int rc = rel3[n];
    const unsigned short* pa = (const unsigned short*)(megaT + (size_t)n * MT_LD + MT_P3);
    const unsigned short* pw = (const unsigned short*)(w2b + (size_t)rc * 32);
    float acc = 0.f;
    #pragma unroll
    for (int k = 0; k < 32; ++k) acc += bfl(pa[k]) * bfl(pw[k]);
    tt2[n] = acc;
}

// ================= stage C: fat kernel (all tails streaming, barrier-free K-loops) =================
#define NT3 1024   // 128 rowgroups x 8 colsplits (211 tiles each)
#define NT1 512    // 256 rowgroups(16) x 2 colsplits (32 tiles each)
#define NT2 512    // 128 rowgroups(32) x 4 colsplits (48 tiles each)
__global__ __launch_bounds__(256) void fatC(const __hip_bfloat16* __restrict__ megaT,
        const __hip_bfloat16* __restrict__ t1w2b, const __hip_bfloat16* __restrict__ t2w2b,
        const __hip_bfloat16* __restrict__ w2b3,
        const int* __restrict__ rel1, const int* __restrict__ rel2, const int* __restrict__ rel3,
        float* __restrict__ S1, float* __restrict__ S2, float* __restrict__ pS3,
        float* __restrict__ tt0, float* __restrict__ tt1, float* __restrict__ tt2) {
    __shared__ float red[128];
    int idx = blockIdx.x, tid = threadIdx.x;
    if (idx < NT3) { t3_partial_body(megaT, w2b3, pS3, idx, tid, red); return; }
    idx -= NT3;
    if (idx < NT1) {
        int rg = idx >> 1, cs = idx & 1;
        stream_lse<16,16>(megaT, MT_LD, t1w2b, 512, rg, cs * 32, 32, rel1, S1, tt0, red);
        return;
    }
    idx -= NT1;
    if (idx < NT2) {
        int rg = idx >> 2, cs = idx & 3;
        stream_lse<4,32>(megaT + MT_P2, MT_LD, t2w2b, 128, rg, cs * 48, 48, rel2, S2, tt1, red);
        return;
    }
    idx -= NT2;
    t3_gather_body(megaT, w2b3, rel3, tt2, idx, tid);
}

// ================= stage E: final assembly =================
__global__ __launch_bounds__(256) void final_kernel(const float* __restrict__ aux,
        const int* __restrict__ targets,
        const float* __restrict__ S0, const float* __restrict__ S1, const float* __restrict__ S2,
        const float* __restrict__ pS3,
        const float* __restrict__ tt0, const float* __restrict__ tt1, const float* __restrict__ tt2,
        float* __restrict__ out) {
    int n = blockIdx.x * 256 + threadIdx.x;
    float local = 0.f;
    if (n < NR) {
        float E = __builtin_amdgcn_exp2f(LSE_NC);      // exp(0 - SHIFT): exact pad-col term
        int b = n / (SS - 1), t = n % (SS - 1);
        int lbl = targets[b * SS + t + 1];
        float lse = logf(S0[n]) + LSE_SHIFT;
        float o;
        if (lbl < 1000)      o = aux[n*8 + 0] - lse;
        else if (lbl < 2000) o = (aux[n*8 + 2] - lse) + (tt0[n] - (logf(S1[n] - 24.f*E) + LSE_SHIFT));
        else if (lbl < 5000) o = (aux[n*8 + 3] - lse) + (tt1[n] - (logf(S2[n] - 72.f*E) + LSE_SHIFT));
        else {
            float S3 = 0.f;
            #pragma unroll
            for (int c = 0; c < 8; ++c) S3 += pS3[n*8 + c];
            S3 -= 8.0f * E;
            o = (aux[n*8 + 4] - lse) + (tt2[n] - (logf(S3) + LSE_SHIFT));
        }
        local = o;
    }
    local = block_sum256(local);
    if (threadIdx.x == 0) atomicAdd(out, -local / (float)NR);
}

extern "C" void kernel_launch(void* const* d_in, const int* in_sizes, int n_in,
                              void* d_out, int out_size, void* d_ws, size_t ws_size,
                              hipStream_t stream) {
    const float* x      = (const float*)d_in[0];
    const int*   targets= (const int*)d_in[1];
    const float* gamma  = (const float*)d_in[2];
    const float* beta   = (const float*)d_in[3];
    const float* head_w = (const float*)d_in[4];
    const float* t1_w1  = (const float*)d_in[5];
    const float* t1_w2  = (const float*)d_in[6];
    const float* t2_w1  = (const float*)d_in[7];
    const float* t2_w2  = (const float*)d_in[8];
    const float* t3_w1  = (const float*)d_in[9];
    const float* t3_w2  = (const float*)d_in[10];
    (void)in_sizes; (void)n_in; (void)out_size; (void)ws_size;

    char* base = (char*)d_ws;
    size_t off = 0;
    auto ab = [&](size_t nbytes) { char* p = base + off; off += (nbytes + 15) & ~(size_t)15; return p; };
    unsigned char* h8     = (unsigned char*)ab((size_t)NRP * DD);              // 8.4 MB fp8
    unsigned char* w1cat8 = (unsigned char*)ab((size_t)MC_LD * DD);            // 3.7 MB fp8
    __hip_bfloat16* P     = (__hip_bfloat16*)ab((size_t)2 * NRP * MC_LD * 2);  // 29.4 MB
    __hip_bfloat16* megaT = (__hip_bfloat16*)ab((size_t)NRP * MT_LD * 2);      // 6.3 MB
    __hip_bfloat16* t1w2b = (__hip_bfloat16*)ab((size_t)1024 * 512 * 2);
    __hip_bfloat16* t2w2b = (__hip_bfloat16*)ab((size_t)3072 * 128 * 2);
    __hip_bfloat16* w2b3  = (__hip_bfloat16*)ab((size_t)27008 * 32 * 2);
    float* aux = (float*)ab((size_t)NRP * 8 * 4);
    float* pS3 = (float*)ab((size_t)NRP * 8 * 4);
    float* S0  = (float*)ab(NRP * 4);
    float* S1  = (float*)ab(NRP * 4);
    float* S2  = (float*)ab(NRP * 4);
    int* relH  = (int*)ab(NRP * 4);
    int* rel1  = (int*)ab(NRP * 4);
    int* rel2  = (int*)ab(NRP * 4);
    int* rel3  = (int*)ab(NRP * 4);
    float* tt0 = (float*)ab(NRP * 4);
    float* tt1 = (float*)ab(NRP * 4);
    float* tt2 = (float*)ab(NRP * 4);

    AParams p;
    p.x = x; p.gamma = gamma; p.beta = beta; p.h8 = h8;
    p.targets = targets;
    p.relH = relH; p.rel1 = rel1; p.rel2 = rel2; p.rel3 = rel3;
    p.S1 = S1; p.S2 = S2; p.out = (float*)d_out;
    const float* srcs[7] = {head_w, t1_w1, t2_w1, t3_w1, t1_w2, t2_w2, t3_w2};
    void* dsts[7] = {w1cat8, w1cat8 + (size_t)1024*2048, w1cat8 + (size_t)1536*2048,
                     w1cat8 + (size_t)1664*2048, t1w2b, t2w2b, w2b3};
    int nsrc[7] = {1003*2048, 512*2048, 128*2048, 32*2048, 1000*512, 3000*128, 27000*32};
    int ntot[7] = {1024*2048, 512*2048, 128*2048, 128*2048, 1024*512, 3072*128, 27008*32};
    int isf8[7] = {1, 1, 1, 1, 0, 0, 0};
    int blk = 0;
    for (int i = 0; i < 7; ++i) {
        p.sg.src[i] = srcs[i]; p.sg.dst[i] = dsts[i];
        p.sg.n_src[i] = nsrc[i]; p.sg.n_tot[i] = ntot[i];
        p.sg.isfp8[i] = isf8[i];
        p.sg.b0[i] = blk;
        blk += (ntot[i] + 1023) / 1024;
    }
    p.castBlocks = blk;

    stageA<<<NRP + blk + 16, 256, 0, stream>>>(p);
    mega_sk<<<dim3(14, 32, 2), 256, 0, stream>>>(h8, w1cat8, P);
    combine_head<<<NRP, 256, 0, stream>>>(P, megaT, relH, S0, aux);
    fatC<<<NT3 + NT1 + NT2 + 16, 256, 0, stream>>>(megaT, t1w2b, t2w2b, w2b3,
            rel1, rel2, rel3, S1, S2, pS3, tt0, tt1, tt2);
    final_kernel<<<16, 256, 0, stream>>>(aux, targets, S0, S1, S2, pS3, tt0, tt1, tt2, (float*)d_out);
}

// Round 11
// 193.275 us; speedup vs baseline: 1.1453x; 1.1453x over previous
//
#include <hip/hip_runtime.h>
#include <hip/hip_bf16.h>
#include <math.h>

#define BB 2
#define SS 2048
#define DD 2048
#define NR (BB*(SS-1))      // 4094 valid rows
#define NRP 4096            // padded rows
#define MT_LD 768           // compact proj layout: [p1 512 | p2 128 | p3 32 | pad]
#define MT_P2 512
#define MT_P3 640

#define L2E 1.4426950408889634f
#define LSE_SHIFT 4.0f
#define LSE_NC (-LSE_SHIFT * L2E)
#define WSCALE 16.0f        // fp8 weight pre-scale (avoids e4m3 subnormals at |w|~0.02)
#define WINV   0.0625f

typedef short  bh8   __attribute__((ext_vector_type(8)));
typedef float  f32x4 __attribute__((ext_vector_type(4)));
typedef long   l64x2 __attribute__((ext_vector_type(2)));   // 16 B = two fp8 MFMA operands

__device__ inline float bfl(unsigned short b) { return __uint_as_float(((unsigned)b) << 16); }
__device__ inline float expsh(float v) { return __builtin_amdgcn_exp2f(fmaf(v, L2E, LSE_NC)); }

__device__ inline float block_sum256(float v) {
    __shared__ float tmp[4];
    #pragma unroll
    for (int o = 32; o > 0; o >>= 1) v += __shfl_down(v, o, 64);
    int lane = threadIdx.x & 63, w = threadIdx.x >> 6;
    if (lane == 0) tmp[w] = v;
    __syncthreads();
    float r = tmp[0] + tmp[1] + tmp[2] + tmp[3];
    __syncthreads();
    return r;
}

// pack 4 floats -> 4 e4m3 bytes (HW cvt, saturating)
__device__ inline unsigned pack_fp8x4(float a, float b, float c, float d) {
    unsigned r = 0;
    r = __builtin_amdgcn_cvt_pk_fp8_f32(a, b, r, false);   // bytes 0-1
    r = __builtin_amdgcn_cvt_pk_fp8_f32(c, d, r, true);    // bytes 2-3
    return r;
}

// ================= stage A: LN + weight casts + index/zero init, ONE launch =================
struct CastSegs {
    const float* src[7];
    void* dst[7];
    int n_src[7];
    int n_tot[7];
    int b0[7];
    int isfp8[7];       // 1: fp8 e4m3 scaled by WSCALE; 0: bf16
};
struct AParams {
    const float* x; const float* gamma; const float* beta;
    unsigned char* h8;                                 // fp8 h [4096][2048]
    CastSegs sg; int castBlocks;
    const int* targets;
    int *relH, *rel1, *rel2, *rel3;
    float *S0, *S1, *S2, *out;
};

__global__ __launch_bounds__(256) void stageA(AParams p) {
    int blk = blockIdx.x, tid = threadIdx.x;
    if (blk < NRP) {                                   // ---- LayerNorm role -> fp8 h ----
        int n = blk;
        unsigned char* hr = p.h8 + (size_t)n * DD;
        if (n >= NR) { *(uint2*)(hr + tid * 8) = make_uint2(0,0); return; }
        int b = n / (SS - 1), t = n % (SS - 1);
        const float4* xr = (const float4*)(p.x + (size_t)(b * SS + t) * DD);
        float4 a = xr[tid * 2];
        float4 c = xr[tid * 2 + 1];
        float sum = a.x + a.y + a.z + a.w + c.x + c.y + c.z + c.w;
        sum = block_sum256(sum);
        float mu = sum * (1.0f / DD);
        float d[8] = {a.x-mu, a.y-mu, a.z-mu, a.w-mu, c.x-mu, c.y-mu, c.z-mu, c.w-mu};
        float sq = 0.f;
        #pragma unroll
        for (int i = 0; i < 8; ++i) sq += d[i] * d[i];
        sq = block_sum256(sq);
        float rstd = rsqrtf(sq * (1.0f / DD) + 1e-5f);
        const float4* g4 = (const float4*)p.gamma;
        const float4* be4 = (const float4*)p.beta;
        float4 g1 = g4[tid*2], g2 = g4[tid*2+1];
        float4 b1 = be4[tid*2], b2 = be4[tid*2+1];
        float gg[8] = {g1.x,g1.y,g1.z,g1.w,g2.x,g2.y,g2.z,g2.w};
        float bb[8] = {b1.x,b1.y,b1.z,b1.w,b2.x,b2.y,b2.z,b2.w};
        float o[8];
        #pragma unroll
        for (int i = 0; i < 8; ++i) o[i] = d[i] * rstd * gg[i] + bb[i];
        uint2 pk;
        pk.x = pack_fp8x4(o[0], o[1], o[2], o[3]);
        pk.y = pack_fp8x4(o[4], o[5], o[6], o[7]);
        *(uint2*)(hr + tid * 8) = pk;
        return;
    }
    blk -= NRP;
    if (blk < p.castBlocks) {                          // ---- weight cast role ----
        int k = 0;
        #pragma unroll
        for (int i = 1; i < 7; ++i) if (blk >= p.sg.b0[i]) k = i;
        int i4 = (blk - p.sg.b0[k]) * 1024 + tid * 4;
        if (i4 >= p.sg.n_tot[k]) return;
        float4 v = make_float4(0.f,0.f,0.f,0.f);
        if (i4 < p.sg.n_src[k]) v = *(const float4*)(p.sg.src[k] + i4);
        if (p.sg.isfp8[k]) {
            unsigned pk = pack_fp8x4(v.x * WSCALE, v.y * WSCALE, v.z * WSCALE, v.w * WSCALE);
            *(unsigned*)((unsigned char*)p.sg.dst[k] + i4) = pk;
        } else {
            __align__(8) __hip_bfloat16 o[4] = {
                __float2bfloat16(v.x), __float2bfloat16(v.y),
                __float2bfloat16(v.z), __float2bfloat16(v.w)};
            *(uint2*)((__hip_bfloat16*)p.sg.dst[k] + i4) = *(uint2*)o;
        }
        return;
    }
    blk -= p.castBlocks;                               // ---- init role (16 blocks) ----
    int n = blk * 256 + tid;
    if (n >= NRP) return;
    int lbl = -1;
    if (n < NR) {
        int b = n / (SS - 1), t = n % (SS - 1);
        lbl = p.targets[b * SS + t + 1];
    }
    bool v = n < NR;
    p.relH[n] = v ? (lbl < 1000 ? lbl : 999) : -1;
    int r1 = lbl - 1000;  p.rel1[n] = v ? (r1 < 0 ? 0 : (r1 > 999   ? 999   : r1)) : -1;
    int r2 = lbl - 2000;  p.rel2[n] = v ? (r2 < 0 ? 0 : (r2 > 2999  ? 2999  : r2)) : -1;
    int r3 = lbl - 5000;  p.rel3[n] = v ? (r3 < 0 ? 0 : (r3 > 26999 ? 26999 : r3)) : -1;
    p.S0[n] = 0.f; p.S1[n] = 0.f; p.S2[n] = 0.f;
    if (n == 0) p.out[0] = 0.f;
}

// ================= stage B: mega GEMM fp8, 128x128 tile, BK=64, full K, fused head epilogue ====
// grid dim3(14, 32). bx<8: head cols -> fixed-shift exp-sum + target/cluster gathers, NO store.
// bx>=8: proj cols -> write compact bf16 megaT. Uniform K=2048 keeps block durations equal
// (R7's regression was the mixed-K grid, not the fusion). ds_read_b128 k-perm trick [R9-verified].
__global__ __launch_bounds__(256) void megaF(
        const unsigned char* __restrict__ A,           // h8 [4096][2048] fp8
        const unsigned char* __restrict__ W,           // w1cat8 [1792][2048] fp8 (x16)
        __hip_bfloat16* __restrict__ megaT,            // [4096][768]
        const int* __restrict__ relH,
        float* __restrict__ S0, float* __restrict__ aux) {
    __shared__ __align__(16) unsigned char As[128 * 64];   // 8 KB
    __shared__ __align__(16) unsigned char Ws[128 * 64];   // 8 KB
    int tid = threadIdx.x, wv = tid >> 6, lane = tid & 63;
    int row0 = blockIdx.y * 128, col0 = blockIdx.x * 128;
    int wrow = (wv >> 1) * 64, wcol = (wv & 1) * 64;
    f32x4 acc[4][4];
    #pragma unroll
    for (int i = 0; i < 4; ++i)
        #pragma unroll
        for (int j = 0; j < 4; ++j) acc[i][j] = (f32x4){0.f,0.f,0.f,0.f};
    int sr = lane >> 2;           // row within 16-row chunk
    int kp = (lane & 3) * 16;     // byte offset within 64B row (staging)
    int mrow = lane & 15;
    int q16 = (lane >> 4) * 16;   // frag b128 byte offset

    for (int k0 = 0; k0 < DD; k0 += 64) {
        __syncthreads();
        #pragma unroll
        for (int i = 0; i < 2; ++i) {
            int chunk = wv * 2 + i;                    // 8 chunks of 16 rows
            int r = chunk * 16 + sr;
            const void* ga = A + (size_t)(row0 + r) * DD + k0 + kp;
            const void* gw = W + (size_t)(col0 + r) * DD + k0 + kp;
            void* la = (char*)As + chunk * 1024 + lane * 16;
            void* lw = (char*)Ws + chunk * 1024 + lane * 16;
            __builtin_amdgcn_global_load_lds(
                (const __attribute__((address_space(1))) void*)ga,
                (__attribute__((address_space(3))) void*)la, 16, 0, 0);
            __builtin_amdgcn_global_load_lds(
                (const __attribute__((address_space(1))) void*)gw,
                (__attribute__((address_space(3))) void*)lw, 16, 0, 0);
        }
        __syncthreads();
        l64x2 af[4], bfr[4];
        #pragma unroll
        for (int t = 0; t < 4; ++t) {
            af[t]  = *(const l64x2*)(As + (wrow + t*16 + mrow) * 64 + q16);
            bfr[t] = *(const l64x2*)(Ws + (wcol + t*16 + mrow) * 64 + q16);
        }
        #pragma unroll
        for (int s = 0; s < 2; ++s)
            #pragma unroll
            for (int i = 0; i < 4; ++i)
                #pragma unroll
                for (int j = 0; j < 4; ++j)
                    acc[i][j] = __builtin_amdgcn_mfma_f32_16x16x32_fp8_fp8(
                        af[i][s], bfr[j][s], acc[i][j], 0, 0, 0);
    }
    int ccol = lane & 15, g = lane >> 4;
    if (blockIdx.x < 8) {                              // ---- head: fused LSE, no store ----
        int grs[4][4], rh[4][4];
        float ps[4][4];
        #pragma unroll
        for (int i = 0; i < 4; ++i)
            #pragma unroll
            for (int r = 0; r < 4; ++r) {
                grs[i][r] = row0 + wrow + i*16 + g*4 + r;
                rh[i][r] = relH[grs[i][r]];
                ps[i][r] = 0.f;
            }
        #pragma unroll
        for (int i = 0; i < 4; ++i)
            #pragma unroll
            for (int j = 0; j < 4; ++j) {
                int gc = col0 + wcol + j*16 + ccol;
                bool inr = gc < 1003;
                #pragma unroll
                for (int r = 0; r < 4; ++r) {
                    float v = acc[i][j][r] * WINV;
                    if (gc == rh[i][r]) aux[grs[i][r]*8 + 0] = v;
                    if (gc >= 1000 && gc < 1003) aux[grs[i][r]*8 + 2 + (gc - 1000)] = v;
                    ps[i][r] += inr ? expsh(v) : 0.f;
                }
            }
        #pragma unroll
        for (int off = 1; off < 16; off <<= 1)         // reduce over the 16 ccol lanes
            #pragma unroll
            for (int i = 0; i < 4; ++i)
                #pragma unroll
                for (int r = 0; r < 4; ++r) ps[i][r] += __shfl_xor(ps[i][r], off, 64);
        if (ccol == 0)
            #pragma unroll
            for (int i = 0; i < 4; ++i)
                #pragma unroll
                for (int r = 0; r < 4; ++r) atomicAdd(&S0[grs[i][r]], ps[i][r]);
    } else {                                           // ---- proj: write compact megaT ----
        int cb = col0 - 1024 + wcol;
        #pragma unroll
        for (int i = 0; i < 4; ++i) {
            size_t gr0 = row0 + wrow + i*16 + g*4;
            #pragma unroll
            for (int j = 0; j < 4; ++j) {
                size_t gc = cb + j*16 + ccol;
                #pragma unroll
                for (int r = 0; r < 4; ++r)
                    megaT[(gr0 + r) * MT_LD + gc] = __float2bfloat16(acc[i][j][r] * WINV);
            }
        }
    }
}

// ================= stage C device parts (R9-measured-good, verbatim) =================
__device__ void tail_gemm(const __hip_bfloat16* A, int lda,
        const __hip_bfloat16* W, int K, int bx, int by, int validCols,
        const int* rel, float* S, float* tgt, char* sm) {
    __hip_bfloat16* As = (__hip_bfloat16*)sm;          // 4 KB
    __hip_bfloat16* Ws = (__hip_bfloat16*)(sm + 4096); // 8 KB
    int tid = threadIdx.x, wv = tid >> 6, lane = tid & 63;
    int row0 = by * 64, col0 = bx * 128;
    int wrow = (wv >> 1) * 32, wcol = (wv & 1) * 64;
    f32x4 acc[2][4];
    #pragma unroll
    for (int i = 0; i < 2; ++i)
        #pragma unroll
        for (int j = 0; j < 4; ++j) acc[i][j] = (f32x4){0.f,0.f,0.f,0.f};
    int sr = lane >> 2, sk = (lane & 3) * 8, mrow = lane & 15, q16 = (lane >> 4) * 16;

    for (int k0 = 0; k0 < K; k0 += 32) {
        __syncthreads();
        #pragma unroll
        for (int i = 0; i < 3; ++i) {
            int c = wv * 3 + i;
            const __hip_bfloat16* gsrc;
            char* ldst;
            if (c < 4) {
                gsrc = A + (size_t)(row0 + c * 16 + sr) * lda + k0 + sk;
                ldst = (char*)As + c * 1024 + lane * 16;
            } else {
                int cw = c - 4;
                gsrc = W + (size_t)(col0 + cw * 16 + sr) * K + k0 + sk;
                ldst = (char*)Ws + cw * 1024 + lane * 16;
            }
            __builtin_amdgcn_global_load_lds(
                (const __attribute__((address_space(1))) void*)gsrc,
                (__attribute__((address_space(3))) void*)ldst, 16, 0, 0);
        }
        __syncthreads();
        bh8 af[2], bfr[4];
        #pragma unroll
        for (int t = 0; t < 2; ++t)
            af[t] = *(const bh8*)((const char*)As + (wrow + t*16 + mrow) * 64 + q16);
        #pragma unroll
        for (int t = 0; t < 4; ++t)
            bfr[t] = *(const bh8*)((const char*)Ws + (wcol + t*16 + mrow) * 64 + q16);
        #pragma unroll
        for (int i = 0; i < 2; ++i)
            #pragma unroll
            for (int j = 0; j < 4; ++j)
                acc[i][j] = __builtin_amdgcn_mfma_f32_16x16x32_bf16(af[i], bfr[j], acc[i][j], 0, 0, 0);
    }
    int ccol = lane & 15, g = lane >> 4;
    int grs[2][4], rh[2][4];
    float p[2][4];
    #pragma unroll
    for (int i = 0; i < 2; ++i)
        #pragma unroll
        for (int r = 0; r < 4; ++r) {
            grs[i][r] = row0 + wrow + i*16 + g*4 + r;
            rh[i][r] = rel[grs[i][r]];
            p[i][r] = 0.f;
        }
    #pragma unroll
    for (int i = 0; i < 2; ++i)
        #pragma unroll
        for (int j = 0; j < 4; ++j) {
            int gc = col0 + wcol + j*16 + ccol;
            bool inr = gc < validCols;
            #pragma unroll
            for (int r = 0; r < 4; ++r) {
                float v = acc[i][j][r];
                if (gc == rh[i][r]) tgt[grs[i][r]] = v;
                p[i][r] += inr ? expsh(v) : 0.f;
            }
        }
    #pragma unroll
    for (int off = 1; off < 16; off <<= 1)
        #pragma unroll
        for (int i = 0; i < 2; ++i)
            #pragma unroll
            for (int r = 0; r < 4; ++r) p[i][r] += __shfl_xor(p[i][r], off, 64);
    if (ccol == 0)
        #pragma unroll
        for (int i = 0; i < 2; ++i)
            #pragma unroll
            for (int r = 0; r < 4; ++r) atomicAdd(&S[grs[i][r]], p[i][r]);
}

__device__ void t3_partial_body(const __hip_bfloat16* megaT,
        const __hip_bfloat16* w2b, float* pS, int idx, int tid, float* red /*[4][32]*/) {
    int rg = idx >> 3, cs = idx & 7;
    int wv = tid >> 6, lane = tid & 63;
    int q = lane >> 4, cm = lane & 15;
    int row0 = rg * 32;
    bh8 af0 = *(const bh8*)(megaT + (size_t)(row0 + cm) * MT_LD + MT_P3 + q * 8);
    bh8 af1 = *(const bh8*)(megaT + (size_t)(row0 + 16 + cm) * MT_LD + MT_P3 + q * 8);
    int tile0 = cs * 211, tile1 = tile0 + 211;
    float s0[4] = {0,0,0,0}, s1[4] = {0,0,0,0};
    bh8 bf = *(const bh8*)(w2b + (size_t)((tile0 + wv) * 16 + cm) * 32 + q * 8);
    for (int ot = tile0 + wv; ot < tile1; ot += 4) {
        int otn = ot + 4;
        bh8 bfn = bf;
        if (otn < tile1)
            bfn = *(const bh8*)(w2b + (size_t)(otn * 16 + cm) * 32 + q * 8);
        f32x4 c0 = __builtin_amdgcn_mfma_f32_16x16x32_bf16(af0, bf, (f32x4){0,0,0,0}, 0, 0, 0);
        f32x4 c1 = __builtin_amdgcn_mfma_f32_16x16x32_bf16(af1, bf, (f32x4){0,0,0,0}, 0, 0, 0);
        #pragma unroll
        for (int r = 0; r < 4; ++r) { s0[r] += expsh(c0[r]); s1[r] += expsh(c1[r]); }
        bf = bfn;
    }
    #pragma unroll
    for (int off = 1; off < 16; off <<= 1)
        #pragma unroll
        for (int r = 0; r < 4; ++r) {
            s0[r] += __shfl_xor(s0[r], off, 64);
            s1[r] += __shfl_xor(s1[r], off, 64);
        }
    if (cm == 0)
        #pragma unroll
        for (int r = 0; r < 4; ++r) {
            red[wv * 32 + q * 4 + r]      = s0[r];
            red[wv * 32 + 16 + q * 4 + r] = s1[r];
        }
    __syncthreads();
    if (tid < 32)
        pS[(size_t)(row0 + tid) * 8 + cs] = red[tid] + red[32 + tid] + red[64 + tid] + red[96 + tid];
}

__device__ void t3_gather_body(const __hip_bfloat16* megaT, const __hip_bfloat16* w2b,
        const int* rel3, float* tt2, int idx, int tid) {
    int n = idx * 256 + tid;
    if (n >= NR) return;
    int rc = rel3[n];
    const unsigned short* pa = (const unsigned short*)(megaT + (size_t)n * MT_LD + MT_P3);
    const unsigned short* pw = (const unsigned short*)(w2b + (size_t)rc * 32);
    float acc = 0.f;
    #pragma unroll
    for (int k = 0; k < 32; ++k) acc += bfl(pa[k]) * bfl(pw[k]);
    tt2[n] = acc;
}

// ================= stage C: fat kernel (tails only) — R9-measured-good =================
#define NT3 1024
#define NT1 512
#define NT2 1536
__global__ __launch_bounds__(256) void fatC(const __hip_bfloat16* __restrict__ megaT,
        const __hip_bfloat16* __restrict__ t1w2b, const __hip_bfloat16* __restrict__ t2w2b,
        const __hip_bfloat16* __restrict__ w2b3,
        const int* __restrict__ rel1, const int* __restrict__ rel2, const int* __restrict__ rel3,
        float* __restrict__ S1, float* __restrict__ S2, float* __restrict__ pS3,
        float* __restrict__ tt0, float* __restrict__ tt1, float* __restrict__ tt2) {
    __shared__ __align__(16) char sm[12288];
    int idx = blockIdx.x, tid = threadIdx.x;
    if (idx < NT3) { t3_partial_body(megaT, w2b3, pS3, idx, tid, (float*)sm); return; }
    idx -= NT3;
    if (idx < NT1) { tail_gemm(megaT, MT_LD, t1w2b, 512, idx % 8, idx / 8, 1000, rel1, S1, tt0, sm); return; }
    idx -= NT1;
    if (idx < NT2) { tail_gemm(megaT + MT_P2, MT_LD, t2w2b, 128, idx % 24, idx / 24, 3000, rel2, S2, tt1, sm); return; }
    idx -= NT2;
    t3_gather_body(megaT, w2b3, rel3, tt2, idx, tid);
}

// ================= stage E: final assembly =================
__global__ __launch_bounds__(256) void final_kernel(const float* __restrict__ aux,
        const int* __restrict__ targets,
        const float* __restrict__ S0, const float* __restrict__ S1, const float* __restrict__ S2,
        const float* __restrict__ pS3,
        const float* __restrict__ tt0, const float* __restrict__ tt1, const float* __restrict__ tt2,
        float* __restrict__ out) {
    int n = blockIdx.x * 256 + threadIdx.x;
    float local = 0.f;
    if (n < NR) {
        int b = n / (SS - 1), t = n % (SS - 1);
        int lbl = targets[b * SS + t + 1];
        float lse = logf(S0[n]) + LSE_SHIFT;
        float o;
        if (lbl < 1000)      o = aux[n*8 + 0] - lse;
        else if (lbl < 2000) o = (aux[n*8 + 2] - lse) + (tt0[n] - (logf(S1[n]) + LSE_SHIFT));
        else if (lbl < 5000) o = (aux[n*8 + 3] - lse) + (tt1[n] - (logf(S2[n]) + LSE_SHIFT));
        else {
            float S3 = 0.f;
            #pragma unroll
            for (int c = 0; c < 8; ++c) S3 += pS3[n*8 + c];
            S3 -= 8.0f * __builtin_amdgcn_exp2f(LSE_NC);       // exact pad-col correction
            o = (aux[n*8 + 4] - lse) + (tt2[n] - (logf(S3) + LSE_SHIFT));
        }
        local = o;
    }
    local = block_sum256(local);
    if (threadIdx.x == 0) atomicAdd(out, -local / (float)NR);
}

extern "C" void kernel_launch(void* const* d_in, const int* in_sizes, int n_in,
                              void* d_out, int out_size, void* d_ws, size_t ws_size,
                              hipStream_t stream) {
    const float* x      = (const float*)d_in[0];
    const int*   targets= (const int*)d_in[1];
    const float* gamma  = (const float*)d_in[2];
    const float* beta   = (const float*)d_in[3];
    const float* head_w = (const float*)d_in[4];
    const float* t1_w1  = (const float*)d_in[5];
    const float* t1_w2  = (const float*)d_in[6];
    const float* t2_w1  = (const float*)d_in[7];
    const float* t2_w2  = (const float*)d_in[8];
    const float* t3_w1  = (const float*)d_in[9];
    const float* t3_w2  = (const float*)d_in[10];
    (void)in_sizes; (void)n_in; (void)out_size; (void)ws_size;

    char* base = (char*)d_ws;
    size_t off = 0;
    auto ab = [&](size_t nbytes) { char* p = base + off; off += (nbytes + 15) & ~(size_t)15; return p; };
    unsigned char* h8     = (unsigned char*)ab((size_t)NRP * DD);              // 8.4 MB fp8
    unsigned char* w1cat8 = (unsigned char*)ab((size_t)1792 * DD);             // 3.7 MB fp8
    __hip_bfloat16* megaT = (__hip_bfloat16*)ab((size_t)NRP * MT_LD * 2);      // 6.3 MB
    __hip_bfloat16* t1w2b = (__hip_bfloat16*)ab((size_t)1024 * 512 * 2);
    __hip_bfloat16* t2w2b = (__hip_bfloat16*)ab((size_t)3072 * 128 * 2);
    __hip_bfloat16* w2b3  = (__hip_bfloat16*)ab((size_t)27008 * 32 * 2);
    float* aux = (float*)ab((size_t)NRP * 8 * 4);
    float* pS3 = (float*)ab((size_t)NRP * 8 * 4);
    float* S0  = (float*)ab(NRP * 4);
    float* S1  = (float*)ab(NRP * 4);
    float* S2  = (float*)ab(NRP * 4);
    int* relH  = (int*)ab(NRP * 4);
    int* rel1  = (int*)ab(NRP * 4);
    int* rel2  = (int*)ab(NRP * 4);
    int* rel3  = (int*)ab(NRP * 4);
    float* tt0 = (float*)ab(NRP * 4);
    float* tt1 = (float*)ab(NRP * 4);
    float* tt2 = (float*)ab(NRP * 4);

    AParams p;
    p.x = x; p.gamma = gamma; p.beta = beta; p.h8 = h8;
    p.targets = targets;
    p.relH = relH; p.rel1 = rel1; p.rel2 = rel2; p.rel3 = rel3;
    p.S0 = S0; p.S1 = S1; p.S2 = S2; p.out = (float*)d_out;
    const float* srcs[7] = {head_w, t1_w1, t2_w1, t3_w1, t1_w2, t2_w2, t3_w2};
    void* dsts[7] = {w1cat8, w1cat8 + (size_t)1024*2048, w1cat8 + (size_t)1536*2048,
                     w1cat8 + (size_t)1664*2048, t1w2b, t2w2b, w2b3};
    int nsrc[7] = {1003*2048, 512*2048, 128*2048, 32*2048, 1000*512, 3000*128, 27000*32};
    int ntot[7] = {1024*2048, 512*2048, 128*2048, 128*2048, 1024*512, 3072*128, 27008*32};
    int isf8[7] = {1, 1, 1, 1, 0, 0, 0};
    int blk = 0;
    for (int i = 0; i < 7; ++i) {
        p.sg.src[i] = srcs[i]; p.sg.dst[i] = dsts[i];
        p.sg.n_src[i] = nsrc[i]; p.sg.n_tot[i] = ntot[i];
        p.sg.isfp8[i] = isf8[i];
        p.sg.b0[i] = blk;
        blk += (ntot[i] + 1023) / 1024;
    }
    p.castBlocks = blk;

    stageA<<<NRP + blk + 16, 256, 0, stream>>>(p);
    megaF<<<dim3(14, 32), 256, 0, stream>>>(h8, w1cat8, megaT, relH, S0, aux);
    fatC<<<NT3 + NT1 + NT2 + 16, 256, 0, stream>>>(megaT, t1w2b, t2w2b, w2b3,
            rel1, rel2, rel3, S1, S2, pS3, tt0, tt1, tt2);
    final_kernel<<<16, 256, 0, stream>>>(aux, targets, S0, S1, S2, pS3, tt0, tt1, tt2, (float*)d_out);
}

// Round 12
// 186.981 us; speedup vs baseline: 1.1839x; 1.0337x over previous
//
#include <hip/hip_runtime.h>
#include <hip/hip_bf16.h>
#include <math.h>

#define BB 2
#define SS 2048
#define DD 2048
#define NR (BB*(SS-1))      // 4094 valid rows
#define NRP 4096            // padded rows
#define MT_LD 768           // compact proj layout: [p1 512 | p2 128 | p3 32 | pad]
#define MT_P2 512
#define MT_P3 640

#define L2E 1.4426950408889634f
#define LSE_SHIFT 4.0f
#define LSE_NC (-LSE_SHIFT * L2E)
#define WSCALE 16.0f        // fp8 weight pre-scale (avoids e4m3 subnormals at |w|~0.02)
#define WINV   0.0625f

typedef short  bh8   __attribute__((ext_vector_type(8)));
typedef float  f32x4 __attribute__((ext_vector_type(4)));
typedef long   l64x2 __attribute__((ext_vector_type(2)));   // 16 B = two fp8 MFMA operands

__device__ inline float bfl(unsigned short b) { return __uint_as_float(((unsigned)b) << 16); }
__device__ inline float expsh(float v) { return __builtin_amdgcn_exp2f(fmaf(v, L2E, LSE_NC)); }

__device__ inline float block_sum256(float v) {
    __shared__ float tmp[4];
    #pragma unroll
    for (int o = 32; o > 0; o >>= 1) v += __shfl_down(v, o, 64);
    int lane = threadIdx.x & 63, w = threadIdx.x >> 6;
    if (lane == 0) tmp[w] = v;
    __syncthreads();
    float r = tmp[0] + tmp[1] + tmp[2] + tmp[3];
    __syncthreads();
    return r;
}

// pack 4 floats -> 4 e4m3 bytes (HW cvt, saturating)
__device__ inline unsigned pack_fp8x4(float a, float b, float c, float d) {
    unsigned r = 0;
    r = __builtin_amdgcn_cvt_pk_fp8_f32(a, b, r, false);   // bytes 0-1
    r = __builtin_amdgcn_cvt_pk_fp8_f32(c, d, r, true);    // bytes 2-3
    return r;
}

// ================= stage A: LN + weight casts + index/zero init, ONE launch =================
struct CastSegs {
    const float* src[7];
    void* dst[7];
    int n_src[7];
    int n_tot[7];
    int b0[7];
    int isfp8[7];       // 1: fp8 e4m3 scaled by WSCALE; 0: bf16
};
struct AParams {
    const float* x; const float* gamma; const float* beta;
    unsigned char* h8;                                 // fp8 h [4096][2048]
    CastSegs sg; int castBlocks;
    const int* targets;
    int *relH, *rel1, *rel2, *rel3;
    float *S0, *S1, *S2, *out;
};

__global__ __launch_bounds__(256) void stageA(AParams p) {
    int blk = blockIdx.x, tid = threadIdx.x;
    if (blk < NRP) {                                   // ---- LayerNorm role -> fp8 h ----
        int n = blk;
        unsigned char* hr = p.h8 + (size_t)n * DD;
        if (n >= NR) { *(uint2*)(hr + tid * 8) = make_uint2(0,0); return; }
        int b = n / (SS - 1), t = n % (SS - 1);
        const float4* xr = (const float4*)(p.x + (size_t)(b * SS + t) * DD);
        float4 a = xr[tid * 2];
        float4 c = xr[tid * 2 + 1];
        float sum = a.x + a.y + a.z + a.w + c.x + c.y + c.z + c.w;
        sum = block_sum256(sum);
        float mu = sum * (1.0f / DD);
        float d[8] = {a.x-mu, a.y-mu, a.z-mu, a.w-mu, c.x-mu, c.y-mu, c.z-mu, c.w-mu};
        float sq = 0.f;
        #pragma unroll
        for (int i = 0; i < 8; ++i) sq += d[i] * d[i];
        sq = block_sum256(sq);
        float rstd = rsqrtf(sq * (1.0f / DD) + 1e-5f);
        const float4* g4 = (const float4*)p.gamma;
        const float4* be4 = (const float4*)p.beta;
        float4 g1 = g4[tid*2], g2 = g4[tid*2+1];
        float4 b1 = be4[tid*2], b2 = be4[tid*2+1];
        float gg[8] = {g1.x,g1.y,g1.z,g1.w,g2.x,g2.y,g2.z,g2.w};
        float bb[8] = {b1.x,b1.y,b1.z,b1.w,b2.x,b2.y,b2.z,b2.w};
        float o[8];
        #pragma unroll
        for (int i = 0; i < 8; ++i) o[i] = d[i] * rstd * gg[i] + bb[i];
        uint2 pk;
        pk.x = pack_fp8x4(o[0], o[1], o[2], o[3]);
        pk.y = pack_fp8x4(o[4], o[5], o[6], o[7]);
        *(uint2*)(hr + tid * 8) = pk;
        return;
    }
    blk -= NRP;
    if (blk < p.castBlocks) {                          // ---- weight cast role ----
        int k = 0;
        #pragma unroll
        for (int i = 1; i < 7; ++i) if (blk >= p.sg.b0[i]) k = i;
        int i4 = (blk - p.sg.b0[k]) * 1024 + tid * 4;
        if (i4 >= p.sg.n_tot[k]) return;
        float4 v = make_float4(0.f,0.f,0.f,0.f);
        if (i4 < p.sg.n_src[k]) v = *(const float4*)(p.sg.src[k] + i4);
        if (p.sg.isfp8[k]) {
            unsigned pk = pack_fp8x4(v.x * WSCALE, v.y * WSCALE, v.z * WSCALE, v.w * WSCALE);
            *(unsigned*)((unsigned char*)p.sg.dst[k] + i4) = pk;
        } else {
            __align__(8) __hip_bfloat16 o[4] = {
                __float2bfloat16(v.x), __float2bfloat16(v.y),
                __float2bfloat16(v.z), __float2bfloat16(v.w)};
            *(uint2*)((__hip_bfloat16*)p.sg.dst[k] + i4) = *(uint2*)o;
        }
        return;
    }
    blk -= p.castBlocks;                               // ---- init role (16 blocks) ----
    int n = blk * 256 + tid;
    if (n >= NRP) return;
    int lbl = -1;
    if (n < NR) {
        int b = n / (SS - 1), t = n % (SS - 1);
        lbl = p.targets[b * SS + t + 1];
    }
    bool v = n < NR;
    p.relH[n] = v ? (lbl < 1000 ? lbl : 999) : -1;
    int r1 = lbl - 1000;  p.rel1[n] = v ? (r1 < 0 ? 0 : (r1 > 999   ? 999   : r1)) : -1;
    int r2 = lbl - 2000;  p.rel2[n] = v ? (r2 < 0 ? 0 : (r2 > 2999  ? 2999  : r2)) : -1;
    int r3 = lbl - 5000;  p.rel3[n] = v ? (r3 < 0 ? 0 : (r3 > 26999 ? 26999 : r3)) : -1;
    p.S0[n] = 0.f; p.S1[n] = 0.f; p.S2[n] = 0.f;
    if (n == 0) p.out[0] = 0.f;
}

// ================= stage B: mega GEMM fp8, 128x128 tile, BK=64, full K, fused head epilogue ====
// [R11-measured-good, verbatim]
__global__ __launch_bounds__(256) void megaF(
        const unsigned char* __restrict__ A,           // h8 [4096][2048] fp8
        const unsigned char* __restrict__ W,           // w1cat8 [1792][2048] fp8 (x16)
        __hip_bfloat16* __restrict__ megaT,            // [4096][768]
        const int* __restrict__ relH,
        float* __restrict__ S0, float* __restrict__ aux) {
    __shared__ __align__(16) unsigned char As[128 * 64];   // 8 KB
    __shared__ __align__(16) unsigned char Ws[128 * 64];   // 8 KB
    int tid = threadIdx.x, wv = tid >> 6, lane = tid & 63;
    int row0 = blockIdx.y * 128, col0 = blockIdx.x * 128;
    int wrow = (wv >> 1) * 64, wcol = (wv & 1) * 64;
    f32x4 acc[4][4];
    #pragma unroll
    for (int i = 0; i < 4; ++i)
        #pragma unroll
        for (int j = 0; j < 4; ++j) acc[i][j] = (f32x4){0.f,0.f,0.f,0.f};
    int sr = lane >> 2;           // row within 16-row chunk
    int kp = (lane & 3) * 16;     // byte offset within 64B row (staging)
    int mrow = lane & 15;
    int q16 = (lane >> 4) * 16;   // frag b128 byte offset

    for (int k0 = 0; k0 < DD; k0 += 64) {
        __syncthreads();
        #pragma unroll
        for (int i = 0; i < 2; ++i) {
            int chunk = wv * 2 + i;                    // 8 chunks of 16 rows
            int r = chunk * 16 + sr;
            const void* ga = A + (size_t)(row0 + r) * DD + k0 + kp;
            const void* gw = W + (size_t)(col0 + r) * DD + k0 + kp;
            void* la = (char*)As + chunk * 1024 + lane * 16;
            void* lw = (char*)Ws + chunk * 1024 + lane * 16;
            __builtin_amdgcn_global_load_lds(
                (const __attribute__((address_space(1))) void*)ga,
                (__attribute__((address_space(3))) void*)la, 16, 0, 0);
            __builtin_amdgcn_global_load_lds(
                (const __attribute__((address_space(1))) void*)gw,
                (__attribute__((address_space(3))) void*)lw, 16, 0, 0);
        }
        __syncthreads();
        l64x2 af[4], bfr[4];
        #pragma unroll
        for (int t = 0; t < 4; ++t) {
            af[t]  = *(const l64x2*)(As + (wrow + t*16 + mrow) * 64 + q16);
            bfr[t] = *(const l64x2*)(Ws + (wcol + t*16 + mrow) * 64 + q16);
        }
        #pragma unroll
        for (int s = 0; s < 2; ++s)
            #pragma unroll
            for (int i = 0; i < 4; ++i)
                #pragma unroll
                for (int j = 0; j < 4; ++j)
                    acc[i][j] = __builtin_amdgcn_mfma_f32_16x16x32_fp8_fp8(
                        af[i][s], bfr[j][s], acc[i][j], 0, 0, 0);
    }
    int ccol = lane & 15, g = lane >> 4;
    if (blockIdx.x < 8) {                              // ---- head: fused LSE, no store ----
        int grs[4][4], rh[4][4];
        float ps[4][4];
        #pragma unroll
        for (int i = 0; i < 4; ++i)
            #pragma unroll
            for (int r = 0; r < 4; ++r) {
                grs[i][r] = row0 + wrow + i*16 + g*4 + r;
                rh[i][r] = relH[grs[i][r]];
                ps[i][r] = 0.f;
            }
        #pragma unroll
        for (int i = 0; i < 4; ++i)
            #pragma unroll
            for (int j = 0; j < 4; ++j) {
                int gc = col0 + wcol + j*16 + ccol;
                bool inr = gc < 1003;
                #pragma unroll
                for (int r = 0; r < 4; ++r) {
                    float v = acc[i][j][r] * WINV;
                    if (gc == rh[i][r]) aux[grs[i][r]*8 + 0] = v;
                    if (gc >= 1000 && gc < 1003) aux[grs[i][r]*8 + 2 + (gc - 1000)] = v;
                    ps[i][r] += inr ? expsh(v) : 0.f;
                }
            }
        #pragma unroll
        for (int off = 1; off < 16; off <<= 1)         // reduce over the 16 ccol lanes
            #pragma unroll
            for (int i = 0; i < 4; ++i)
                #pragma unroll
                for (int r = 0; r < 4; ++r) ps[i][r] += __shfl_xor(ps[i][r], off, 64);
        if (ccol == 0)
            #pragma unroll
            for (int i = 0; i < 4; ++i)
                #pragma unroll
                for (int r = 0; r < 4; ++r) atomicAdd(&S0[grs[i][r]], ps[i][r]);
    } else {                                           // ---- proj: write compact megaT ----
        int cb = col0 - 1024 + wcol;
        #pragma unroll
        for (int i = 0; i < 4; ++i) {
            size_t gr0 = row0 + wrow + i*16 + g*4;
            #pragma unroll
            for (int j = 0; j < 4; ++j) {
                size_t gc = cb + j*16 + ccol;
                #pragma unroll
                for (int r = 0; r < 4; ++r)
                    megaT[(gr0 + r) * MT_LD + gc] = __float2bfloat16(acc[i][j][r] * WINV);
            }
        }
    }
}

// ================= stage C device parts =================
// tail GEMM (R9-measured-good, verbatim)
__device__ void tail_gemm(const __hip_bfloat16* A, int lda,
        const __hip_bfloat16* W, int K, int bx, int by, int validCols,
        const int* rel, float* S, float* tgt, char* sm) {
    __hip_bfloat16* As = (__hip_bfloat16*)sm;          // 4 KB
    __hip_bfloat16* Ws = (__hip_bfloat16*)(sm + 4096); // 8 KB
    int tid = threadIdx.x, wv = tid >> 6, lane = tid & 63;
    int row0 = by * 64, col0 = bx * 128;
    int wrow = (wv >> 1) * 32, wcol = (wv & 1) * 64;
    f32x4 acc[2][4];
    #pragma unroll
    for (int i = 0; i < 2; ++i)
        #pragma unroll
        for (int j = 0; j < 4; ++j) acc[i][j] = (f32x4){0.f,0.f,0.f,0.f};
    int sr = lane >> 2, sk = (lane & 3) * 8, mrow = lane & 15, q16 = (lane >> 4) * 16;

    for (int k0 = 0; k0 < K; k0 += 32) {
        __syncthreads();
        #pragma unroll
        for (int i = 0; i < 3; ++i) {
            int c = wv * 3 + i;
            const __hip_bfloat16* gsrc;
            char* ldst;
            if (c < 4) {
                gsrc = A + (size_t)(row0 + c * 16 + sr) * lda + k0 + sk;
                ldst = (char*)As + c * 1024 + lane * 16;
            } else {
                int cw = c - 4;
                gsrc = W + (size_t)(col0 + cw * 16 + sr) * K + k0 + sk;
                ldst = (char*)Ws + cw * 1024 + lane * 16;
            }
            __builtin_amdgcn_global_load_lds(
                (const __attribute__((address_space(1))) void*)gsrc,
                (__attribute__((address_space(3))) void*)ldst, 16, 0, 0);
        }
        __syncthreads();
        bh8 af[2], bfr[4];
        #pragma unroll
        for (int t = 0; t < 2; ++t)
            af[t] = *(const bh8*)((const char*)As + (wrow + t*16 + mrow) * 64 + q16);
        #pragma unroll
        for (int t = 0; t < 4; ++t)
            bfr[t] = *(const bh8*)((const char*)Ws + (wcol + t*16 + mrow) * 64 + q16);
        #pragma unroll
        for (int i = 0; i < 2; ++i)
            #pragma unroll
            for (int j = 0; j < 4; ++j)
                acc[i][j] = __builtin_amdgcn_mfma_f32_16x16x32_bf16(af[i], bfr[j], acc[i][j], 0, 0, 0);
    }
    int ccol = lane & 15, g = lane >> 4;
    int grs[2][4], rh[2][4];
    float p[2][4];
    #pragma unroll
    for (int i = 0; i < 2; ++i)
        #pragma unroll
        for (int r = 0; r < 4; ++r) {
            grs[i][r] = row0 + wrow + i*16 + g*4 + r;
            rh[i][r] = rel[grs[i][r]];
            p[i][r] = 0.f;
        }
    #pragma unroll
    for (int i = 0; i < 2; ++i)
        #pragma unroll
        for (int j = 0; j < 4; ++j) {
            int gc = col0 + wcol + j*16 + ccol;
            bool inr = gc < validCols;
            #pragma unroll
            for (int r = 0; r < 4; ++r) {
                float v = acc[i][j][r];
                if (gc == rh[i][r]) tgt[grs[i][r]] = v;
                p[i][r] += inr ? expsh(v) : 0.f;
            }
        }
    #pragma unroll
    for (int off = 1; off < 16; off <<= 1)
        #pragma unroll
        for (int i = 0; i < 2; ++i)
            #pragma unroll
            for (int r = 0; r < 4; ++r) p[i][r] += __shfl_xor(p[i][r], off, 64);
    if (ccol == 0)
        #pragma unroll
        for (int i = 0; i < 2; ++i)
            #pragma unroll
            for (int r = 0; r < 4; ++r) atomicAdd(&S[grs[i][r]], p[i][r]);
}

// t3: 64 rows/block (4 MFMAs per b-frag load — halves w2 L2 traffic), 2-deep prefetch
__device__ void t3_partial_body(const __hip_bfloat16* megaT,
        const __hip_bfloat16* w2b, float* pS, int idx, int tid, float* red /*[4][64]*/) {
    int rg = idx >> 3, cs = idx & 7;       // rg in [0,64): 64 rows each
    int wv = tid >> 6, lane = tid & 63;
    int q = lane >> 4, cm = lane & 15;
    int row0 = rg * 64;
    bh8 af[4];
    #pragma unroll
    for (int h = 0; h < 4; ++h)
        af[h] = *(const bh8*)(megaT + (size_t)(row0 + h*16 + cm) * MT_LD + MT_P3 + q * 8);
    int tile0 = cs * 211, tile1 = tile0 + 211;    // 8*211 == 1688
    float s[4][4];
    #pragma unroll
    for (int h = 0; h < 4; ++h)
        #pragma unroll
        for (int r = 0; r < 4; ++r) s[h][r] = 0.f;
    // 2-deep prefetch (addresses clamped; over-prefetched values never consumed)
    int ot = tile0 + wv;
    int oc0 = ot < tile1 ? ot : tile1 - 1;
    int oc1 = ot + 4 < tile1 ? ot + 4 : tile1 - 1;
    bh8 b0 = *(const bh8*)(w2b + (size_t)(oc0 * 16 + cm) * 32 + q * 8);
    bh8 b1 = *(const bh8*)(w2b + (size_t)(oc1 * 16 + cm) * 32 + q * 8);
    for (; ot < tile1; ot += 4) {
        bh8 bcur = b0;
        b0 = b1;
        int otn = ot + 8;
        if (otn < tile1)
            b1 = *(const bh8*)(w2b + (size_t)(otn * 16 + cm) * 32 + q * 8);
        f32x4 c[4];
        #pragma unroll
        for (int h = 0; h < 4; ++h)
            c[h] = __builtin_amdgcn_mfma_f32_16x16x32_bf16(af[h], bcur, (f32x4){0,0,0,0}, 0, 0, 0);
        #pragma unroll
        for (int h = 0; h < 4; ++h)
            #pragma unroll
            for (int r = 0; r < 4; ++r) s[h][r] += expsh(c[h][r]);
    }
    #pragma unroll
    for (int off = 1; off < 16; off <<= 1)
        #pragma unroll
        for (int h = 0; h < 4; ++h)
            #pragma unroll
            for (int r = 0; r < 4; ++r) s[h][r] += __shfl_xor(s[h][r], off, 64);
    if (cm == 0)
        #pragma unroll
        for (int h = 0; h < 4; ++h)
            #pragma unroll
            for (int r = 0; r < 4; ++r)
                red[wv * 64 + h*16 + q*4 + r] = s[h][r];
    __syncthreads();
    if (tid < 64)
        pS[(size_t)(row0 + tid) * 8 + cs] = red[tid] + red[64 + tid] + red[128 + tid] + red[192 + tid];
}

__device__ void t3_gather_body(const __hip_bfloat16* megaT, const __hip_bfloat16* w2b,
        const int* rel3, float* tt2, int idx, int tid) {
    int n = idx * 256 + tid;
    if (n >= NR) return;
    int rc = rel3[n];
    const unsigned short* pa = (const unsigned short*)(megaT + (size_t)n * MT_LD + MT_P3);
    const unsigned short* pw = (const unsigned short*)(w2b + (size_t)rc * 32);
    float acc = 0.f;
    #pragma unroll
    for (int k = 0; k < 32; ++k) acc += bfl(pa[k]) * bfl(pw[k]);
    tt2[n] = acc;
}

// ================= stage C: fat kernel (tails only) =================
#define NT3 512    // 64 rowgroups(64) x 8 colsplits
#define NT1 512
#define NT2 1536
__global__ __launch_bounds__(256) void fatC(const __hip_bfloat16* __restrict__ megaT,
        const __hip_bfloat16* __restrict__ t1w2b, const __hip_bfloat16* __restrict__ t2w2b,
        const __hip_bfloat16* __restrict__ w2b3,
        const int* __restrict__ rel1, const int* __restrict__ rel2, const int* __restrict__ rel3,
        float* __restrict__ S1, float* __restrict__ S2, float* __restrict__ pS3,
        float* __restrict__ tt0, float* __restrict__ tt1, float* __restrict__ tt2) {
    __shared__ __align__(16) char sm[12288];
    int idx = blockIdx.x, tid = threadIdx.x;
    if (idx < NT3) { t3_partial_body(megaT, w2b3, pS3, idx, tid, (float*)sm); return; }
    idx -= NT3;
    if (idx < NT1) { tail_gemm(megaT, MT_LD, t1w2b, 512, idx % 8, idx / 8, 1000, rel1, S1, tt0, sm); return; }
    idx -= NT1;
    if (idx < NT2) { tail_gemm(megaT + MT_P2, MT_LD, t2w2b, 128, idx % 24, idx / 24, 3000, rel2, S2, tt1, sm); return; }
    idx -= NT2;
    t3_gather_body(megaT, w2b3, rel3, tt2, idx, tid);
}

// ================= stage E: final assembly =================
__global__ __launch_bounds__(256) void final_kernel(const float* __restrict__ aux,
        const int* __restrict__ targets,
        const float* __restrict__ S0, const float* __restrict__ S1, const float* __restrict__ S2,
        const float* __restrict__ pS3,
        const float* __restrict__ tt0, const float* __restrict__ tt1, const float* __restrict__ tt2,
        float* __restrict__ out) {
    int n = blockIdx.x * 256 + threadIdx.x;
    float local = 0.f;
    if (n < NR) {
        int b = n / (SS - 1), t = n % (SS - 1);
        int lbl = targets[b * SS + t + 1];
        float lse = logf(S0[n]) + LSE_SHIFT;
        float o;
        if (lbl < 1000)      o = aux[n*8 + 0] - lse;
        else if (lbl < 2000) o = (aux[n*8 + 2] - lse) + (tt0[n] - (logf(S1[n]) + LSE_SHIFT));
        else if (lbl < 5000) o = (aux[n*8 + 3] - lse) + (tt1[n] - (logf(S2[n]) + LSE_SHIFT));
        else {
            float S3 = 0.f;
            #pragma unroll
            for (int c = 0; c < 8; ++c) S3 += pS3[n*8 + c];
            S3 -= 8.0f * __builtin_amdgcn_exp2f(LSE_NC);       // exact pad-col correction
            o = (aux[n*8 + 4] - lse) + (tt2[n] - (logf(S3) + LSE_SHIFT));
        }
        local = o;
    }
    local = block_sum256(local);
    if (threadIdx.x == 0) atomicAdd(out, -local / (float)NR);
}

extern "C" void kernel_launch(void* const* d_in, const int* in_sizes, int n_in,
                              void* d_out, int out_size, void* d_ws, size_t ws_size,
                              hipStream_t stream) {
    const float* x      = (const float*)d_in[0];
    const int*   targets= (const int*)d_in[1];
    const float* gamma  = (const float*)d_in[2];
    const float* beta   = (const float*)d_in[3];
    const float* head_w = (const float*)d_in[4];
    const float* t1_w1  = (const float*)d_in[5];
    const float* t1_w2  = (const float*)d_in[6];
    const float* t2_w1  = (const float*)d_in[7];
    const float* t2_w2  = (const float*)d_in[8];
    const float* t3_w1  = (const float*)d_in[9];
    const float* t3_w2  = (const float*)d_in[10];
    (void)in_sizes; (void)n_in; (void)out_size; (void)ws_size;

    char* base = (char*)d_ws;
    size_t off = 0;
    auto ab = [&](size_t nbytes) { char* p = base + off; off += (nbytes + 15) & ~(size_t)15; return p; };
    unsigned char* h8     = (unsigned char*)ab((size_t)NRP * DD);              // 8.4 MB fp8
    unsigned char* w1cat8 = (unsigned char*)ab((size_t)1792 * DD);             // 3.7 MB fp8
    __hip_bfloat16* megaT = (__hip_bfloat16*)ab((size_t)NRP * MT_LD * 2);      // 6.3 MB
    __hip_bfloat16* t1w2b = (__hip_bfloat16*)ab((size_t)1024 * 512 * 2);
    __hip_bfloat16* t2w2b = (__hip_bfloat16*)ab((size_t)3072 * 128 * 2);
    __hip_bfloat16* w2b3  = (__hip_bfloat16*)ab((size_t)27008 * 32 * 2);
    float* aux = (float*)ab((size_t)NRP * 8 * 4);
    float* pS3 = (float*)ab((size_t)NRP * 8 * 4);
    float* S0  = (float*)ab(NRP * 4);
    float* S1  = (float*)ab(NRP * 4);
    float* S2  = (float*)ab(NRP * 4);
    int* relH  = (int*)ab(NRP * 4);
    int* rel1  = (int*)ab(NRP * 4);
    int* rel2  = (int*)ab(NRP * 4);
    int* rel3  = (int*)ab(NRP * 4);
    float* tt0 = (float*)ab(NRP * 4);
    float* tt1 = (float*)ab(NRP * 4);
    float* tt2 = (float*)ab(NRP * 4);

    AParams p;
    p.x = x; p.gamma = gamma; p.beta = beta; p.h8 = h8;
    p.targets = targets;
    p.relH = relH; p.rel1 = rel1; p.rel2 = rel2; p.rel3 = rel3;
    p.S0 = S0; p.S1 = S1; p.S2 = S2; p.out = (float*)d_out;
    const float* srcs[7] = {head_w, t1_w1, t2_w1, t3_w1, t1_w2, t2_w2, t3_w2};
    void* dsts[7] = {w1cat8, w1cat8 + (size_t)1024*2048, w1cat8 + (size_t)1536*2048,
                     w1cat8 + (size_t)1664*2048, t1w2b, t2w2b, w2b3};
    int nsrc[7] = {1003*2048, 512*2048, 128*2048, 32*2048, 1000*512, 3000*128, 27000*32};
    int ntot[7] = {1024*2048, 512*2048, 128*2048, 128*2048, 1024*512, 3072*128, 27008*32};
    int isf8[7] = {1, 1, 1, 1, 0, 0, 0};
    int blk = 0;
    for (int i = 0; i < 7; ++i) {
        p.sg.src[i] = srcs[i]; p.sg.dst[i] = dsts[i];
        p.sg.n_src[i] = nsrc[i]; p.sg.n_tot[i] = ntot[i];
        p.sg.isfp8[i] = isf8[i];
        p.sg.b0[i] = blk;
        blk += (ntot[i] + 1023) / 1024;
    }
    p.castBlocks = blk;

    stageA<<<NRP + blk + 16, 256, 0, stream>>>(p);
    megaF<<<dim3(14, 32), 256, 0, stream>>>(h8, w1cat8, megaT, relH, S0, aux);
    fatC<<<NT3 + NT1 + NT2 + 16, 256, 0, stream>>>(megaT, t1w2b, t2w2b, w2b3,
            rel1, rel2, rel3, S1, S2, pS3, tt0, tt1, tt2);
    final_kernel<<<16, 256, 0, stream>>>(aux, targets, S0, S1, S2, pS3, tt0, tt1, tt2, (float*)d_out);
}